// Round 4
// baseline (757.832 us; speedup 1.0000x reference)
//
#include <hip/hip_runtime.h>
#include <hip/hip_bf16.h>

#define N_NODES 50000
#define NREL 16
#define HID 64
#define NCLS 16
#define NBKT (N_NODES * NREL)       // 800000 buckets (dst*16 + rel)
#define SB 2048                     // scan elems per block
#define NSB ((NBKT + SB - 1) / SB)  // 391
#define TILE 16                     // dst nodes per fused block (50000/16 exact)
#define NTB (N_NODES / TILE)        // 3125
#define XCHUNKS (N_NODES * HID / 8) // 400000
#define W1N (17 * HID * HID)        // 69632
#define W2N (17 * NCLS * HID)       // 17408
#define ROWW 68                     // f32 row stride: 16B-aligned, bank-rotating

typedef __attribute__((ext_vector_type(8))) short bf16x8;
typedef __attribute__((ext_vector_type(4))) float f32x4;

static __device__ __forceinline__ unsigned short f2bf(float f) {
    __hip_bfloat16 h = __float2bfloat16(f);
    return *reinterpret_cast<unsigned short*>(&h);
}
static __device__ __forceinline__ float bf2f(unsigned short u) {
    __hip_bfloat16 h;
    *reinterpret_cast<unsigned short*>(&h) = u;
    return __bfloat162float(h);
}

// ---------------------------------------------------------------------------
// ws layout:
//   bcnt/rstart i32[800020] (zeroed; scan3 -> prefix IN PLACE)
//   | rank i32[E] | bsum i32[512] | sedge i32[E] (src | rel<<16 | (dst&15)<<20)
//   | WbT1 bf16[17*64*64] [t][n][k] | WbT2 bf16[17*16*64] [t][n][k]
//   | xb bf16[50000*64] | X1b bf16[50000*64]
// Fused layers: per 16-node tile, edge-PARALLEL gather (contiguous slice,
// coalesced descriptors, ds_add_f32 into f32 LDS accumulators), then MFMA
// with on-the-fly mean-scale + bf16 convert of A-fragments.
// ---------------------------------------------------------------------------

// K0: convert x -> bf16 AND build transposed bf16 weights (merged grid)
__global__ __launch_bounds__(256) void cvt_k(const float* __restrict__ x,
                                             const float* __restrict__ W1,
                                             const float* __restrict__ root1,
                                             const float* __restrict__ W2,
                                             const float* __restrict__ root2,
                                             ushort* __restrict__ xb,
                                             ushort* __restrict__ WbT1,
                                             ushort* __restrict__ WbT2) {
    int i = blockIdx.x * 256 + threadIdx.x;
    if (i < XCHUNKS) {
        float4 f0 = *(const float4*)(x + (size_t)i * 8);
        float4 f1 = *(const float4*)(x + (size_t)i * 8 + 4);
        bf16x8 o;
        o[0] = (short)f2bf(f0.x); o[1] = (short)f2bf(f0.y);
        o[2] = (short)f2bf(f0.z); o[3] = (short)f2bf(f0.w);
        o[4] = (short)f2bf(f1.x); o[5] = (short)f2bf(f1.y);
        o[6] = (short)f2bf(f1.z); o[7] = (short)f2bf(f1.w);
        *(bf16x8*)(xb + (size_t)i * 8) = o;
    } else {
        int j = i - XCHUNKS;
        if (j < W1N) {
            int t = j >> 12, rem = j & 4095, n = rem >> 6, k = rem & 63;
            float v = (t < 16) ? W1[(size_t)t * HID * HID + k * HID + n]
                               : root1[k * HID + n];
            WbT1[j] = f2bf(v);
        } else {
            int m = j - W1N;
            if (m < W2N) {
                int t = m >> 10, rem = m & 1023, n = rem >> 6, k = rem & 63;
                float v = (t < 16) ? W2[(size_t)t * HID * NCLS + k * NCLS + n]
                                   : root2[k * NCLS + n];
                WbT2[m] = f2bf(v);
            }
        }
    }
}

// K1: one atomic pass over buckets (dst*16+rel): count + per-edge rank
__global__ __launch_bounds__(256) void rank_k(const int* __restrict__ dstp,
                                              const int* __restrict__ et,
                                              int* __restrict__ bcnt,
                                              int* __restrict__ rank, int E) {
    int i = blockIdx.x * 256 + threadIdx.x;
    if (i < E) {
        int b = dstp[i] * NREL + et[i];
        rank[i] = atomicAdd(&bcnt[b], 1);
    }
}

// K2a: per-block sums of bcnt (2048 elems / block, 8 per thread)
__global__ __launch_bounds__(256) void scan1_k(const int* __restrict__ bcnt,
                                               int* __restrict__ bsum) {
    int b = blockIdx.x, t = threadIdx.x;
    int base = b * SB + t * 8;
    int s = 0;
#pragma unroll
    for (int j = 0; j < 8; ++j)
        if (base + j < NBKT) s += bcnt[base + j];
#pragma unroll
    for (int off = 1; off < 64; off <<= 1) s += __shfl_xor(s, off, 64);
    __shared__ int ws[4];
    if ((t & 63) == 0) ws[t >> 6] = s;
    __syncthreads();
    if (t == 0) bsum[b] = ws[0] + ws[1] + ws[2] + ws[3];
}

// K2b: exclusive scan of bsum[NSB] (one 512-thread block); rstart[NBKT] = E
__global__ __launch_bounds__(512) void scan2_k(int* __restrict__ bsum,
                                               int* __restrict__ rstart, int E) {
    __shared__ int ts[512];
    int t = threadIdx.x;
    int v = (t < NSB) ? bsum[t] : 0;
    ts[t] = v;
    __syncthreads();
    int acc = v;
    for (int off = 1; off < 512; off <<= 1) {
        int u = (t >= off) ? ts[t - off] : 0;
        __syncthreads();
        acc += u;
        ts[t] = acc;
        __syncthreads();
    }
    if (t < NSB) bsum[t] = acc - v;
    if (t == 0) rstart[NBKT] = E;
}

// K2c: per-block exclusive scan, IN PLACE (bcnt -> rstart)
__global__ __launch_bounds__(256) void scan3_k(int* __restrict__ bcnt,
                                               const int* __restrict__ bsum) {
    int b = blockIdx.x, t = threadIdx.x;
    int base = b * SB + t * 8;
    int a[8];
    int s = 0;
#pragma unroll
    for (int j = 0; j < 8; ++j) {
        a[j] = (base + j < NBKT) ? bcnt[base + j] : 0;
        s += a[j];
    }
    __shared__ int ts[256];
    ts[t] = s;
    __syncthreads();
    int acc = s;
    for (int off = 1; off < 256; off <<= 1) {
        int u = (t >= off) ? ts[t - off] : 0;
        __syncthreads();
        acc += u;
        ts[t] = acc;
        __syncthreads();
    }
    int run = bsum[b] + (acc - s);
#pragma unroll
    for (int j = 0; j < 8; ++j) {
        if (base + j < NBKT) bcnt[base + j] = run;
        run += a[j];
    }
}

// K3: atomic-free scatter; pack src | rel<<16 | (dst&15)<<20
__global__ __launch_bounds__(256) void scat_k(const int* __restrict__ srcp,
                                              const int* __restrict__ dstp,
                                              const int* __restrict__ et,
                                              const int* __restrict__ rank,
                                              const int* __restrict__ rstart,
                                              int* __restrict__ sedge, int E) {
    int i = blockIdx.x * 256 + threadIdx.x;
    if (i < E) {
        int r = et[i];
        int d = dstp[i];
        int b = d * NREL + r;
        sedge[rstart[b] + rank[i]] = srcp[i] | (r << 16) | ((d & 15) << 20);
    }
}

// ---------------------------------------------------------------------------
// Edge-parallel gather into f32 LDS accumulators (shared by fuse1/fuse2).
// 32 groups x 8 lanes; group g owns a contiguous run of the tile's edge
// slice; descriptors coalesced; features 8-wide independent; ds_add_f32.
// ---------------------------------------------------------------------------
static __device__ __forceinline__ void gather_f32(float* Acc,
                                                  const ushort* __restrict__ ft,
                                                  const int* __restrict__ sedge,
                                                  int lo, int hi, int tid) {
    int g = tid >> 3, l8 = tid & 7;
    int nE = hi - lo;
    int R = (nE + 31) >> 5;
    int myLo = lo + g * R;
    int myHi = myLo + R;
    if (myHi > hi) myHi = hi;
    const ushort* xcol = ft + l8 * 8;
    const bf16x8 zz = {0, 0, 0, 0, 0, 0, 0, 0};
    for (int base = myLo; base < myHi; base += 8) {
        int d[8];
        bf16x8 f[8];
#pragma unroll
        for (int j = 0; j < 8; ++j)
            d[j] = (base + j < myHi) ? sedge[base + j] : -1;
#pragma unroll
        for (int j = 0; j < 8; ++j) {
            f[j] = zz;
            if (d[j] >= 0)
                f[j] = *(const bf16x8*)(xcol + (size_t)(d[j] & 0xFFFF) * HID);
        }
#pragma unroll
        for (int j = 0; j < 8; ++j) {
            if (d[j] >= 0) {
                int rel = (d[j] >> 16) & 15;
                int nl = (d[j] >> 20) & 15;
                float* rp = Acc + (rel * TILE + nl) * ROWW + l8 * 8;
#pragma unroll
                for (int q = 0; q < 8; ++q)
                    atomicAdd(rp + q, bf2f((unsigned short)f[j][q]));
            }
        }
    }
}

// Load+scale+convert one A-fragment pair from f32 LDS.
#define LOAD_A(T)                                                             \
    const float* arow_ = Acc + ((T)*TILE + mr) * ROWW + kq * 8;               \
    float inv_ = InvL[(T)*TILE + mr];                                         \
    f32x4 v0_ = *(const f32x4*)(arow_);                                       \
    f32x4 v1_ = *(const f32x4*)(arow_ + 4);                                   \
    f32x4 v2_ = *(const f32x4*)(arow_ + 32);                                  \
    f32x4 v3_ = *(const f32x4*)(arow_ + 36);                                  \
    bf16x8 a0, a1;                                                            \
    _Pragma("unroll") for (int j_ = 0; j_ < 4; ++j_) {                        \
        a0[j_] = (short)f2bf(v0_[j_] * inv_);                                 \
        a0[j_ + 4] = (short)f2bf(v1_[j_] * inv_);                             \
        a1[j_] = (short)f2bf(v2_[j_] * inv_);                                 \
        a1[j_ + 4] = (short)f2bf(v3_[j_] * inv_);                             \
    }

__global__ __launch_bounds__(256) void fuse1_k(const ushort* __restrict__ xb,
                                               const int* __restrict__ sedge,
                                               const int* __restrict__ rstart,
                                               const ushort* __restrict__ WbT1,
                                               const float* __restrict__ b1,
                                               ushort* __restrict__ X1b) {
    __shared__ __align__(16) float Acc[NREL * TILE * ROWW];  // 69632 B
    __shared__ float InvL[NREL * TILE];                      // 1024 B
    int tid = threadIdx.x;
    int dst0 = blockIdx.x * TILE;
    int wave = tid >> 6, lane = tid & 63;
    int mr = lane & 15, kq = lane >> 4;

    // root A-frags straight from global (prefetch early)
    const ushort* xrow = xb + (size_t)(dst0 + mr) * HID + kq * 8;
    bf16x8 ra0 = *(const bf16x8*)(xrow);
    bf16x8 ra1 = *(const bf16x8*)(xrow + 32);

    // inverse counts (rstart diffs, coalesced)
    {
        int n = tid >> 4, r = tid & 15;
        int b = (dst0 + n) * NREL + r;
        int c0 = rstart[b], c1 = rstart[b + 1];
        InvL[r * TILE + n] = (c1 > c0) ? 1.0f / (float)(c1 - c0) : 0.0f;
    }
    // zero accumulators: thread t owns row t (68 f32 = 17 x f32x4)
    {
        float* rowp = Acc + tid * ROWW;
        f32x4 z = {0.f, 0.f, 0.f, 0.f};
#pragma unroll
        for (int i = 0; i < 17; ++i) *(f32x4*)(rowp + i * 4) = z;
    }
    int lo = rstart[dst0 * NREL];
    int hi = rstart[(dst0 + TILE) * NREL];
    __syncthreads();

    gather_f32(Acc, xb, sedge, lo, hi, tid);
    __syncthreads();

    // MFMA: wave w owns out cols [w*16, w*16+16); A = 16 nodes x 64
    const ushort* wb = WbT1 + (wave * 16 + mr) * HID + kq * 8;
    f32x4 c = {0.f, 0.f, 0.f, 0.f};
    bf16x8 bk0 = *(const bf16x8*)(wb);
    bf16x8 bk1 = *(const bf16x8*)(wb + 32);
    for (int t = 0; t < 16; ++t) {
        bf16x8 nb0 = *(const bf16x8*)(wb + (t + 1) * (HID * HID));
        bf16x8 nb1 = *(const bf16x8*)(wb + (t + 1) * (HID * HID) + 32);
        LOAD_A(t)
        c = __builtin_amdgcn_mfma_f32_16x16x32_bf16(a0, bk0, c, 0, 0, 0);
        c = __builtin_amdgcn_mfma_f32_16x16x32_bf16(a1, bk1, c, 0, 0, 0);
        bk0 = nb0;
        bk1 = nb1;
    }
    // root (bk now holds t=16 fragments)
    c = __builtin_amdgcn_mfma_f32_16x16x32_bf16(ra0, bk0, c, 0, 0, 0);
    c = __builtin_amdgcn_mfma_f32_16x16x32_bf16(ra1, bk1, c, 0, 0, 0);

    float bias = b1[wave * 16 + mr];
    int col = wave * 16 + mr;
#pragma unroll
    for (int j = 0; j < 4; ++j) {
        int node = dst0 + kq * 4 + j;  // D row = quad*4+reg
        X1b[(size_t)node * HID + col] = f2bf(fmaxf(c[j] + bias, 0.f));
    }
}

__global__ __launch_bounds__(256) void fuse2_k(const ushort* __restrict__ X1b,
                                               const int* __restrict__ sedge,
                                               const int* __restrict__ rstart,
                                               const ushort* __restrict__ WbT2,
                                               const float* __restrict__ b2,
                                               float* __restrict__ out) {
    __shared__ __align__(16) float Acc[NREL * TILE * ROWW];  // 69632 B
    __shared__ float InvL[NREL * TILE];                      // 1024 B
    __shared__ float P[4][TILE * NCLS];                      // 4096 B
    int tid = threadIdx.x;
    int dst0 = blockIdx.x * TILE;
    int wave = tid >> 6, lane = tid & 63;
    int mr = lane & 15, kq = lane >> 4;

    const ushort* xrow = X1b + (size_t)(dst0 + mr) * HID + kq * 8;
    bf16x8 ra0 = *(const bf16x8*)(xrow);
    bf16x8 ra1 = *(const bf16x8*)(xrow + 32);

    {
        int n = tid >> 4, r = tid & 15;
        int b = (dst0 + n) * NREL + r;
        int c0 = rstart[b], c1 = rstart[b + 1];
        InvL[r * TILE + n] = (c1 > c0) ? 1.0f / (float)(c1 - c0) : 0.0f;
    }
    {
        float* rowp = Acc + tid * ROWW;
        f32x4 z = {0.f, 0.f, 0.f, 0.f};
#pragma unroll
        for (int i = 0; i < 17; ++i) *(f32x4*)(rowp + i * 4) = z;
    }
    int lo = rstart[dst0 * NREL];
    int hi = rstart[(dst0 + TILE) * NREL];
    __syncthreads();

    gather_f32(Acc, X1b, sedge, lo, hi, tid);
    __syncthreads();

    // MFMA: out = 16 cols; waves split tasks t = w, w+4, ...; wave 0 adds root
    const ushort* wb = WbT2 + mr * HID + kq * 8;
    f32x4 c = {0.f, 0.f, 0.f, 0.f};
    for (int t = wave; t < 16; t += 4) {
        bf16x8 bk0 = *(const bf16x8*)(wb + t * (NCLS * HID));
        bf16x8 bk1 = *(const bf16x8*)(wb + t * (NCLS * HID) + 32);
        LOAD_A(t)
        c = __builtin_amdgcn_mfma_f32_16x16x32_bf16(a0, bk0, c, 0, 0, 0);
        c = __builtin_amdgcn_mfma_f32_16x16x32_bf16(a1, bk1, c, 0, 0, 0);
    }
    if (wave == 0) {
        bf16x8 bk0 = *(const bf16x8*)(wb + 16 * (NCLS * HID));
        bf16x8 bk1 = *(const bf16x8*)(wb + 16 * (NCLS * HID) + 32);
        c = __builtin_amdgcn_mfma_f32_16x16x32_bf16(ra0, bk0, c, 0, 0, 0);
        c = __builtin_amdgcn_mfma_f32_16x16x32_bf16(ra1, bk1, c, 0, 0, 0);
    }
#pragma unroll
    for (int j = 0; j < 4; ++j) P[wave][(kq * 4 + j) * NCLS + mr] = c[j];
    __syncthreads();

    int row = tid >> 4, cc = tid & 15;
    float s = P[0][tid] + P[1][tid] + P[2][tid] + P[3][tid] + b2[cc];
    out[(size_t)(dst0 + row) * NCLS + cc] = s;
}

extern "C" void kernel_launch(void* const* d_in, const int* in_sizes, int n_in,
                              void* d_out, int out_size, void* d_ws, size_t ws_size,
                              hipStream_t stream) {
    const int* ei    = (const int*)d_in[0];
    const int* et    = (const int*)d_in[1];
    const float* x   = (const float*)d_in[2];
    const float* W1  = (const float*)d_in[3];
    const float* r1  = (const float*)d_in[4];
    const float* b1  = (const float*)d_in[5];
    const float* W2  = (const float*)d_in[6];
    const float* r2  = (const float*)d_in[7];
    const float* b2  = (const float*)d_in[8];
    float* out = (float*)d_out;

    int E = in_sizes[0] / 2;
    const int* srcp = ei;
    const int* dstp = ei + E;

    int*    bcnt  = (int*)d_ws;                 // doubles as rstart after scan3
    int*    rank  = bcnt + (NBKT + 20);
    int*    bsum  = rank + E;                   // 512 ints (NSB=391 used)
    int*    sedge = bsum + 512;
    ushort* WbT1  = (ushort*)(sedge + E);
    ushort* WbT2  = WbT1 + W1N;
    ushort* xb    = WbT2 + W2N;
    ushort* X1b   = xb + (size_t)N_NODES * HID;
    int*    rstart = bcnt;                      // alias (in-place scan)

    hipMemsetAsync(bcnt, 0, (NBKT + 20) * sizeof(int), stream);

    int eb = (E + 255) / 256;
    int cvtThreads = XCHUNKS + W1N + W2N;

    cvt_k<<<(cvtThreads + 255) / 256, 256, 0, stream>>>(x, W1, r1, W2, r2, xb, WbT1, WbT2);
    rank_k<<<eb, 256, 0, stream>>>(dstp, et, bcnt, rank, E);
    scan1_k<<<NSB, 256, 0, stream>>>(bcnt, bsum);
    scan2_k<<<1, 512, 0, stream>>>(bsum, rstart, E);
    scan3_k<<<NSB, 256, 0, stream>>>(bcnt, bsum);
    scat_k<<<eb, 256, 0, stream>>>(srcp, dstp, et, rank, rstart, sedge, E);

    fuse1_k<<<NTB, 256, 0, stream>>>(xb, sedge, rstart, WbT1, b1, X1b);
    fuse2_k<<<NTB, 256, 0, stream>>>(X1b, sedge, rstart, WbT2, b2, out);
}

// Round 5
// 240.208 us; speedup vs baseline: 3.1549x; 3.1549x over previous
//
#include <hip/hip_runtime.h>
#include <hip/hip_bf16.h>

#define N_NODES 50000
#define NREL 16
#define HID 64
#define NCLS 16
#define NBKT (N_NODES * NREL)       // 800000 buckets (dst*16 + rel)
#define SB 2048                     // scan elems per block
#define NSB ((NBKT + SB - 1) / SB)  // 391
#define TILE 32                     // dst nodes per fused block
#define NTB ((N_NODES + TILE - 1) / TILE)  // 1563
#define XCHUNKS (N_NODES * HID / 8)        // 400000
#define W1N (17 * HID * HID)               // 69632
#define W2N (17 * NCLS * HID)              // 17408

typedef __attribute__((ext_vector_type(8))) short bf16x8;
typedef __attribute__((ext_vector_type(4))) float f32x4;

static __device__ __forceinline__ unsigned short f2bf(float f) {
    __hip_bfloat16 h = __float2bfloat16(f);
    return *reinterpret_cast<unsigned short*>(&h);
}
static __device__ __forceinline__ float bf2f(unsigned short u) {
    __hip_bfloat16 h;
    *reinterpret_cast<unsigned short*>(&h) = u;
    return __bfloat162float(h);
}

// ---------------------------------------------------------------------------
// ws layout:
//   bcnt/rstart i32[800020] (zeroed; scan3 -> prefix IN PLACE)
//   | rank i32[E] | bsum i32[512] | sedge int2[E] {src | rel<<16, inv}
//   | WbT1 bf16[17*64*64] [t][n][k] | WbT2 bf16[17*16*64] [t][n][k]
//   | xb bf16[50000*64] | X1b bf16[50000*64]
// Aggregate-then-transform. Gather: node-per-8-lane-group, 32 descriptors
// prefetched, feature loads in 8-wide batches pipelined 2-deep and PINNED
// with sched_barrier(0) so the scheduler cannot sink them (round-3's
// pipeline collapsed at VGPR=88). Mean weight premultiplied per edge.
// ---------------------------------------------------------------------------

// K0: convert x -> bf16 AND build transposed bf16 weights (merged grid)
__global__ __launch_bounds__(256) void cvt_k(const float* __restrict__ x,
                                             const float* __restrict__ W1,
                                             const float* __restrict__ root1,
                                             const float* __restrict__ W2,
                                             const float* __restrict__ root2,
                                             ushort* __restrict__ xb,
                                             ushort* __restrict__ WbT1,
                                             ushort* __restrict__ WbT2) {
    int i = blockIdx.x * 256 + threadIdx.x;
    if (i < XCHUNKS) {
        float4 f0 = *(const float4*)(x + (size_t)i * 8);
        float4 f1 = *(const float4*)(x + (size_t)i * 8 + 4);
        bf16x8 o;
        o[0] = (short)f2bf(f0.x); o[1] = (short)f2bf(f0.y);
        o[2] = (short)f2bf(f0.z); o[3] = (short)f2bf(f0.w);
        o[4] = (short)f2bf(f1.x); o[5] = (short)f2bf(f1.y);
        o[6] = (short)f2bf(f1.z); o[7] = (short)f2bf(f1.w);
        *(bf16x8*)(xb + (size_t)i * 8) = o;
    } else {
        int j = i - XCHUNKS;
        if (j < W1N) {
            int t = j >> 12, rem = j & 4095, n = rem >> 6, k = rem & 63;
            float v = (t < 16) ? W1[(size_t)t * HID * HID + k * HID + n]
                               : root1[k * HID + n];
            WbT1[j] = f2bf(v);
        } else {
            int m = j - W1N;
            if (m < W2N) {
                int t = m >> 10, rem = m & 1023, n = rem >> 6, k = rem & 63;
                float v = (t < 16) ? W2[(size_t)t * HID * NCLS + k * NCLS + n]
                                   : root2[k * NCLS + n];
                WbT2[m] = f2bf(v);
            }
        }
    }
}

// K1: one atomic pass over buckets (dst*16+rel): count + per-edge rank
__global__ __launch_bounds__(256) void rank_k(const int* __restrict__ dstp,
                                              const int* __restrict__ et,
                                              int* __restrict__ bcnt,
                                              int* __restrict__ rank, int E) {
    int i = blockIdx.x * 256 + threadIdx.x;
    if (i < E) {
        int b = dstp[i] * NREL + et[i];
        rank[i] = atomicAdd(&bcnt[b], 1);
    }
}

// K2a: per-block sums of bcnt (2048 elems / block, 8 per thread)
__global__ __launch_bounds__(256) void scan1_k(const int* __restrict__ bcnt,
                                               int* __restrict__ bsum) {
    int b = blockIdx.x, t = threadIdx.x;
    int base = b * SB + t * 8;
    int s = 0;
#pragma unroll
    for (int j = 0; j < 8; ++j)
        if (base + j < NBKT) s += bcnt[base + j];
#pragma unroll
    for (int off = 1; off < 64; off <<= 1) s += __shfl_xor(s, off, 64);
    __shared__ int ws[4];
    if ((t & 63) == 0) ws[t >> 6] = s;
    __syncthreads();
    if (t == 0) bsum[b] = ws[0] + ws[1] + ws[2] + ws[3];
}

// K2b: exclusive scan of bsum[NSB] (one 512-thread block); rstart[NBKT] = E
__global__ __launch_bounds__(512) void scan2_k(int* __restrict__ bsum,
                                               int* __restrict__ rstart, int E) {
    __shared__ int ts[512];
    int t = threadIdx.x;
    int v = (t < NSB) ? bsum[t] : 0;
    ts[t] = v;
    __syncthreads();
    int acc = v;
    for (int off = 1; off < 512; off <<= 1) {
        int u = (t >= off) ? ts[t - off] : 0;
        __syncthreads();
        acc += u;
        ts[t] = acc;
        __syncthreads();
    }
    if (t < NSB) bsum[t] = acc - v;
    if (t == 0) rstart[NBKT] = E;
}

// K2c: per-block exclusive scan, IN PLACE (bcnt -> rstart)
__global__ __launch_bounds__(256) void scan3_k(int* __restrict__ bcnt,
                                               const int* __restrict__ bsum) {
    int b = blockIdx.x, t = threadIdx.x;
    int base = b * SB + t * 8;
    int a[8];
    int s = 0;
#pragma unroll
    for (int j = 0; j < 8; ++j) {
        a[j] = (base + j < NBKT) ? bcnt[base + j] : 0;
        s += a[j];
    }
    __shared__ int ts[256];
    ts[t] = s;
    __syncthreads();
    int acc = s;
    for (int off = 1; off < 256; off <<= 1) {
        int u = (t >= off) ? ts[t - off] : 0;
        __syncthreads();
        acc += u;
        ts[t] = acc;
        __syncthreads();
    }
    int run = bsum[b] + (acc - s);
#pragma unroll
    for (int j = 0; j < 8; ++j) {
        if (base + j < NBKT) bcnt[base + j] = run;
        run += a[j];
    }
}

// K3: atomic-free scatter; int2 {src | rel<<16, 1/cnt} (mean premultiplied)
__global__ __launch_bounds__(256) void scat_k(const int* __restrict__ srcp,
                                              const int* __restrict__ dstp,
                                              const int* __restrict__ et,
                                              const int* __restrict__ rank,
                                              const int* __restrict__ rstart,
                                              int2* __restrict__ sedge, int E) {
    int i = blockIdx.x * 256 + threadIdx.x;
    if (i < E) {
        int r = et[i];
        int b = dstp[i] * NREL + r;
        int lo = rstart[b], hi = rstart[b + 1];
        float inv = 1.0f / (float)(hi - lo);
        sedge[lo + rank[i]] = make_int2(srcp[i] | (r << 16), __float_as_int(inv));
    }
}

// ---------------------------------------------------------------------------
// Fused layer kernels. Per 32-dst tile: build A[17][32][64] bf16 in LDS
// (16 relation means + root), MFMA against all 17 weight slices.
// LDS rows are 128 B -> XOR swizzle byte^=((row&7)<<4) both sides.
// ---------------------------------------------------------------------------

// Flush current relation run to its LDS row (bf16); spurious flush of a
// zero acc to row curRel=0 is harmless (rows are pre-zeroed).
#define GFLUSH()                                                              \
    {                                                                         \
        bf16x8 o_;                                                            \
        o_[0] = (short)f2bf(acc[0]); o_[1] = (short)f2bf(acc[1]);             \
        o_[2] = (short)f2bf(acc[2]); o_[3] = (short)f2bf(acc[3]);             \
        o_[4] = (short)f2bf(acc[4]); o_[5] = (short)f2bf(acc[5]);             \
        o_[6] = (short)f2bf(acc[6]); o_[7] = (short)f2bf(acc[7]);             \
        *(bf16x8*)(Ab + ((curRel * (TILE * 128) + rowoff) ^ sw)) = o_;        \
        acc[0] = 0.f; acc[1] = 0.f; acc[2] = 0.f; acc[3] = 0.f;               \
        acc[4] = 0.f; acc[5] = 0.f; acc[6] = 0.f; acc[7] = 0.f;               \
    }

// Issue 8 independent predicated 16B feature loads for one 8-edge batch.
// W0 keeps the shfl'd descriptor word0 (src|rel) for the consume phase.
#define LOADF(W0, V, DX, JB)                                                  \
    _Pragma("unroll") for (int j8 = 0; j8 < 8; ++j8) {                        \
        W0[j8] = __shfl(DX, gbase + j8, 64);                                  \
        V[j8] = zz;                                                           \
        if ((JB)*8 + j8 < deg)                                                \
            V[j8] = *(const bf16x8*)(xcol + (size_t)(W0[j8] & 0xFFFF) * HID); \
    }

// Consume one batch: rel flush-on-change + weighted accumulate.
#define CONSUME(W0, DY, V, JB)                                                \
    _Pragma("unroll") for (int j8 = 0; j8 < 8; ++j8) {                        \
        if ((JB)*8 + j8 < deg) {                                              \
            int r_ = (W0[j8] >> 16) & 15;                                     \
            if (r_ != curRel) { GFLUSH(); curRel = r_; }                      \
            float inv_ = __int_as_float(__shfl(DY, gbase + j8, 64));          \
            _Pragma("unroll") for (int q = 0; q < 8; ++q)                     \
                acc[q] = fmaf(inv_, bf2f((unsigned short)V[j8][q]), acc[q]);  \
        }                                                                     \
    }

// Shared gather: fills Ab[17][32][64] (swizzled) from feature table ft.
static __device__ __forceinline__ void gather_tile(char* Ab,
                                                   const ushort* __restrict__ ft,
                                                   const int2* __restrict__ sedge,
                                                   const int* __restrict__ rstart,
                                                   int dst0, int tid) {
    int g = tid >> 3, l8 = tid & 7;
    int lane = tid & 63;
    int gbase = lane & 56;
    int node = dst0 + g;
    bool valid = node < N_NODES;

    int lo = 0, hi = 0;
    if (valid) {
        lo = rstart[node * NREL];
        hi = rstart[node * NREL + NREL];
    }

    int sw = (g & 7) << 4;
    int rowoff = (g << 7) + (l8 << 4);
    const bf16x8 zz = {0, 0, 0, 0, 0, 0, 0, 0};

    // prefetch up to 32 packed edge descriptors (4 parallel loads/lane-group)
    int2 d0 = {0, 0}, d1 = {0, 0}, d2 = {0, 0}, d3 = {0, 0};
    int p = lo + l8;
    if (p < hi) d0 = sedge[p];
    if (p + 8 < hi) d1 = sedge[p + 8];
    if (p + 16 < hi) d2 = sedge[p + 16];
    if (p + 24 < hi) d3 = sedge[p + 24];

    // zero relation rows + write root row (overlaps descriptor latency)
#pragma unroll
    for (int t = 0; t < 16; ++t)
        *(bf16x8*)(Ab + ((t * (TILE * 128) + rowoff) ^ sw)) = zz;
    {
        bf16x8 v = zz;
        if (valid) v = *(const bf16x8*)(ft + (size_t)node * HID + l8 * 8);
        *(bf16x8*)(Ab + ((16 * (TILE * 128) + rowoff) ^ sw)) = v;
    }

    int deg = hi - lo;
    const ushort* xcol = ft + l8 * 8;
    float acc[8] = {0.f, 0.f, 0.f, 0.f, 0.f, 0.f, 0.f, 0.f};
    int curRel = 0;

    int w0A[8], w0B[8];
    bf16x8 vA[8], vB[8];
    // 2-deep pipelined batches; sched_barrier(0) pins the load clusters so
    // the scheduler cannot sink them into the consume phase (round-3 bug).
    LOADF(w0A, vA, d0.x, 0)
    LOADF(w0B, vB, d1.x, 1)
    __builtin_amdgcn_sched_barrier(0);
    CONSUME(w0A, d0.y, vA, 0)
    LOADF(w0A, vA, d2.x, 2)
    __builtin_amdgcn_sched_barrier(0);
    CONSUME(w0B, d1.y, vB, 1)
    LOADF(w0B, vB, d3.x, 3)
    __builtin_amdgcn_sched_barrier(0);
    CONSUME(w0A, d2.y, vA, 2)
    CONSUME(w0B, d3.y, vB, 3)

    // rare tail (deg > 32)
    for (int e = lo + 32; e < hi; ++e) {
        int2 m = sedge[e];
        int r = (m.x >> 16) & 15;
        if (r != curRel) {
            GFLUSH();
            curRel = r;
        }
        float inv = __int_as_float(m.y);
        bf16x8 v = *(const bf16x8*)(xcol + (size_t)(m.x & 0xFFFF) * HID);
#pragma unroll
        for (int q = 0; q < 8; ++q)
            acc[q] = fmaf(inv, bf2f((unsigned short)v[q]), acc[q]);
    }
    if (deg > 0) GFLUSH();
}

__global__ __launch_bounds__(256) void fuse1_k(const ushort* __restrict__ xb,
                                               const int2* __restrict__ sedge,
                                               const int* __restrict__ rstart,
                                               const ushort* __restrict__ WbT1,
                                               const float* __restrict__ b1,
                                               ushort* __restrict__ X1b) {
    __shared__ bf16x8 Abuf[17 * TILE * 8];  // 69632 B
    char* Ab = (char*)Abuf;
    int tid = threadIdx.x;
    int dst0 = blockIdx.x * TILE;

    gather_tile(Ab, xb, sedge, rstart, dst0, tid);

    // --- MFMA: wave w owns out cols [w*16, w*16+16), both 16-row m-tiles
    int wave = tid >> 6, lane = tid & 63;
    int mr = lane & 15, kq = lane >> 4;
    f32x4 c0 = {0.f, 0.f, 0.f, 0.f}, c1 = {0.f, 0.f, 0.f, 0.f};
    const ushort* wb = WbT1 + (wave * 16 + mr) * HID + kq * 8;
    int sw = (mr & 7) << 4;
    int a00o = ((mr << 7) + (kq << 4)) ^ sw;
    int a01o = ((mr << 7) + 64 + (kq << 4)) ^ sw;
    int a10o = (((16 + mr) << 7) + (kq << 4)) ^ sw;  // (16+mr)&7 == mr&7
    int a11o = (((16 + mr) << 7) + 64 + (kq << 4)) ^ sw;

    // prefetch t=0 weight fragments before the barrier (overlaps L2 latency)
    bf16x8 bk0 = *(const bf16x8*)(wb);
    bf16x8 bk1 = *(const bf16x8*)(wb + 32);
    __syncthreads();

    for (int t = 0; t < 17; ++t) {
        bf16x8 nb0 = bk0, nb1 = bk1;
        if (t < 16) {
            nb0 = *(const bf16x8*)(wb + (t + 1) * 4096);
            nb1 = *(const bf16x8*)(wb + (t + 1) * 4096 + 32);
        }
        const char* At = Ab + t * (TILE * 128);
        bf16x8 a00 = *(const bf16x8*)(At + a00o);
        bf16x8 a01 = *(const bf16x8*)(At + a01o);
        bf16x8 a10 = *(const bf16x8*)(At + a10o);
        bf16x8 a11 = *(const bf16x8*)(At + a11o);
        c0 = __builtin_amdgcn_mfma_f32_16x16x32_bf16(a00, bk0, c0, 0, 0, 0);
        c0 = __builtin_amdgcn_mfma_f32_16x16x32_bf16(a01, bk1, c0, 0, 0, 0);
        c1 = __builtin_amdgcn_mfma_f32_16x16x32_bf16(a10, bk0, c1, 0, 0, 0);
        c1 = __builtin_amdgcn_mfma_f32_16x16x32_bf16(a11, bk1, c1, 0, 0, 0);
        bk0 = nb0;
        bk1 = nb1;
    }
    float bias = b1[wave * 16 + mr];
    int col = wave * 16 + mr;
#pragma unroll
    for (int j = 0; j < 4; ++j) {
        int r0 = dst0 + kq * 4 + j;  // D row = quad*4+reg
        if (r0 < N_NODES)
            X1b[(size_t)r0 * HID + col] = f2bf(fmaxf(c0[j] + bias, 0.f));
        int r1 = r0 + 16;
        if (r1 < N_NODES)
            X1b[(size_t)r1 * HID + col] = f2bf(fmaxf(c1[j] + bias, 0.f));
    }
}

__global__ __launch_bounds__(256) void fuse2_k(const ushort* __restrict__ X1b,
                                               const int2* __restrict__ sedge,
                                               const int* __restrict__ rstart,
                                               const ushort* __restrict__ WbT2,
                                               const float* __restrict__ b2,
                                               float* __restrict__ out) {
    __shared__ bf16x8 Abuf[17 * TILE * 8];  // 69632 B
    __shared__ float P[4 * TILE * NCLS];    // 8192 B partials (per-wave)
    char* Ab = (char*)Abuf;
    int tid = threadIdx.x;
    int dst0 = blockIdx.x * TILE;

    gather_tile(Ab, X1b, sedge, rstart, dst0, tid);

    // --- MFMA: out cols = 16 only, so waves split the 17 tasks (w, w+4, ...)
    int wave = tid >> 6, lane = tid & 63;
    int mr = lane & 15, kq = lane >> 4;
    f32x4 c0 = {0.f, 0.f, 0.f, 0.f}, c1 = {0.f, 0.f, 0.f, 0.f};
    const ushort* wb = WbT2 + mr * HID + kq * 8;
    int sw = (mr & 7) << 4;
    int a00o = ((mr << 7) + (kq << 4)) ^ sw;
    int a01o = ((mr << 7) + 64 + (kq << 4)) ^ sw;
    int a10o = (((16 + mr) << 7) + (kq << 4)) ^ sw;
    int a11o = (((16 + mr) << 7) + 64 + (kq << 4)) ^ sw;

    bf16x8 bk0 = *(const bf16x8*)(wb + wave * 1024);
    bf16x8 bk1 = *(const bf16x8*)(wb + wave * 1024 + 32);
    __syncthreads();

    for (int t = wave; t < 17; t += 4) {
        bf16x8 nb0 = bk0, nb1 = bk1;
        if (t + 4 < 17) {
            nb0 = *(const bf16x8*)(wb + (t + 4) * 1024);
            nb1 = *(const bf16x8*)(wb + (t + 4) * 1024 + 32);
        }
        const char* At = Ab + t * (TILE * 128);
        bf16x8 a00 = *(const bf16x8*)(At + a00o);
        bf16x8 a01 = *(const bf16x8*)(At + a01o);
        bf16x8 a10 = *(const bf16x8*)(At + a10o);
        bf16x8 a11 = *(const bf16x8*)(At + a11o);
        c0 = __builtin_amdgcn_mfma_f32_16x16x32_bf16(a00, bk0, c0, 0, 0, 0);
        c0 = __builtin_amdgcn_mfma_f32_16x16x32_bf16(a01, bk1, c0, 0, 0, 0);
        c1 = __builtin_amdgcn_mfma_f32_16x16x32_bf16(a10, bk0, c1, 0, 0, 0);
        c1 = __builtin_amdgcn_mfma_f32_16x16x32_bf16(a11, bk1, c1, 0, 0, 0);
        bk0 = nb0;
        bk1 = nb1;
    }
    float* Pw = P + wave * (TILE * NCLS);
#pragma unroll
    for (int j = 0; j < 4; ++j) {
        Pw[(kq * 4 + j) * NCLS + mr] = c0[j];
        Pw[(16 + kq * 4 + j) * NCLS + mr] = c1[j];
    }
    __syncthreads();

    // --- cross-wave reduce + bias; 256 threads x 2 consecutive f32
    int idx = tid * 2;
    int row = idx >> 4, c = idx & 15;
    float s0 = P[idx] + P[512 + idx] + P[1024 + idx] + P[1536 + idx] + b2[c];
    float s1 = P[idx + 1] + P[512 + idx + 1] + P[1024 + idx + 1] +
               P[1536 + idx + 1] + b2[c + 1];
    if (dst0 + row < N_NODES) {
        float2 o = make_float2(s0, s1);
        *(float2*)(out + (size_t)(dst0 + row) * NCLS + c) = o;
    }
}

extern "C" void kernel_launch(void* const* d_in, const int* in_sizes, int n_in,
                              void* d_out, int out_size, void* d_ws, size_t ws_size,
                              hipStream_t stream) {
    const int* ei    = (const int*)d_in[0];
    const int* et    = (const int*)d_in[1];
    const float* x   = (const float*)d_in[2];
    const float* W1  = (const float*)d_in[3];
    const float* r1  = (const float*)d_in[4];
    const float* b1  = (const float*)d_in[5];
    const float* W2  = (const float*)d_in[6];
    const float* r2  = (const float*)d_in[7];
    const float* b2  = (const float*)d_in[8];
    float* out = (float*)d_out;

    int E = in_sizes[0] / 2;
    const int* srcp = ei;
    const int* dstp = ei + E;

    int*    bcnt  = (int*)d_ws;                 // doubles as rstart after scan3
    int*    rank  = bcnt + (NBKT + 20);
    int*    bsum  = rank + E;                   // 512 ints (NSB=391 used)
    int2*   sedge = (int2*)(bsum + 512);
    ushort* WbT1  = (ushort*)(sedge + E);
    ushort* WbT2  = WbT1 + W1N;
    ushort* xb    = WbT2 + W2N;
    ushort* X1b   = xb + (size_t)N_NODES * HID;
    int*    rstart = bcnt;                      // alias (in-place scan)

    hipMemsetAsync(bcnt, 0, (NBKT + 20) * sizeof(int), stream);

    int eb = (E + 255) / 256;
    int cvtThreads = XCHUNKS + W1N + W2N;

    cvt_k<<<(cvtThreads + 255) / 256, 256, 0, stream>>>(x, W1, r1, W2, r2, xb, WbT1, WbT2);
    rank_k<<<eb, 256, 0, stream>>>(dstp, et, bcnt, rank, E);
    scan1_k<<<NSB, 256, 0, stream>>>(bcnt, bsum);
    scan2_k<<<1, 512, 0, stream>>>(bsum, rstart, E);
    scan3_k<<<NSB, 256, 0, stream>>>(bcnt, bsum);
    scat_k<<<eb, 256, 0, stream>>>(srcp, dstp, et, rank, rstart, sedge, E);

    fuse1_k<<<NTB, 256, 0, stream>>>(xb, sedge, rstart, WbT1, b1, X1b);
    fuse2_k<<<NTB, 256, 0, stream>>>(X1b, sedge, rstart, WbT2, b2, out);
}